// Round 10
// baseline (236.460 us; speedup 1.0000x reference)
//
#include <hip/hip_runtime.h>

#define MA 64
#define F 128
#define NF 16
#define HID 512
#define LDUB 144    // ub row stride BYTES (128 fp8 + 16 pad; 16B-aligned, 2-way banks)
#define UBSZ 9216   // per-mol ub bytes (64 x 144)
#define WLB  18432  // wL base byte offset
#define WLSZ 9216   // per-mol wL bytes (64 rows x 144 B)
#define LDWB 144    // wL row stride bytes (64 bf16 + 8 pad elems)
#define LDT1B 1040  // t1 row stride bytes (512 bf16 + 8 pad elems)

typedef float  float4v __attribute__((ext_vector_type(4)));
typedef short  short8  __attribute__((ext_vector_type(8)));
typedef int    int8v   __attribute__((ext_vector_type(8)));

// pack two fp32 -> (bf16(y)<<16)|bf16(x), round-half-up via +0x8000 then v_perm
static __device__ __forceinline__ unsigned int pack2bf(float x, float y) {
    unsigned int a = __float_as_uint(x) + 0x8000u;
    unsigned int b = __float_as_uint(y) + 0x8000u;
    return __builtin_amdgcn_perm(b, a, 0x07060302u);
}
static __device__ __forceinline__ unsigned short f2bf1(float x) {
    return (unsigned short)((__float_as_uint(x) + 0x8000u) >> 16);
}
// pack 4 fp32 -> 4 fp8 e4m3 (RNE, saturating) in one dword
static __device__ __forceinline__ unsigned int pk4fp8(float a, float b, float c, float d) {
    int p = __builtin_amdgcn_cvt_pk_fp8_f32(a, b, 0, false);
    p = __builtin_amdgcn_cvt_pk_fp8_f32(c, d, p, true);
    return (unsigned int)p;
}

// ---- Pack W1 as fp8 MX A-frags (16x16x128: lane l holds A[m0+(l&15)][k0+(l>>4)*32+j],
// j=0..31 = 32 bytes) of W1^T; W2 as bf16 A-frags (16x16x32) of W2^T. Direct gather.
__global__ void pack_frags(const float* __restrict__ W1, const float* __restrict__ W2,
                           unsigned char* __restrict__ w1p, unsigned short* __restrict__ w2p) {
    int gid  = blockIdx.x * 4 + (threadIdx.x >> 6);
    int lane = threadIdx.x & 63;
    int arow = lane & 15;
    int kq   = lane >> 4;
    if (gid < 544) {                           // W1: kt (17 over K=2176, 128 each) x jt (32)
        int kt = gid >> 5, jt = gid & 31;
        const float* base = W1 + (size_t)(kt * 128 + kq * 32) * HID + jt * 16 + arow;
        unsigned int o[8];
        #pragma unroll
        for (int p = 0; p < 8; p++)
            o[p] = pk4fp8(base[(p * 4 + 0) * HID], base[(p * 4 + 1) * HID],
                          base[(p * 4 + 2) * HID], base[(p * 4 + 3) * HID]);
        unsigned char* dst = w1p + ((size_t)gid * 64 + lane) * 32;
        *(uint4*)dst        = (uint4){o[0], o[1], o[2], o[3]};
        *(uint4*)(dst + 16) = (uint4){o[4], o[5], o[6], o[7]};
    } else if (gid < 544 + 128) {              // W2: kt (16 over J=512) x mt (8 over 128)
        int g2 = gid - 544;
        int kt = g2 >> 3, mt = g2 & 7;
        const float* base = W2 + (size_t)(kt * 32 + kq * 8) * F + mt * 16 + arow;
        short8 o;
        #pragma unroll
        for (int j = 0; j < 8; j++) o[j] = (short)f2bf1(base[j * F]);
        *(short8*)(w2p + ((size_t)g2 * 64 + lane) * 8) = o;
    }
}

// ---- Main fused kernel: TWO molecules per block, 512 threads = 8 waves ----
// LDS bytes: ub mol0 @0 (9216) | ub mol1 @9216 (9216) | wL mol0 @18432 (9216)
// | wL mol1 @27648 (9216) = 36864 B. t1 bf16 (32 x 1040 = 33280 B) overlays from 0 in GEMM2.
__launch_bounds__(512, 2)
__global__ void node_conv_mfma(const int* __restrict__ z, const float* __restrict__ rr,
        const float* __restrict__ h, const float* __restrict__ dist,
        const float* __restrict__ wid, const float* __restrict__ b1,
        const float* __restrict__ b2,
        const unsigned char* __restrict__ w1p, const unsigned short* __restrict__ w2p,
        float* __restrict__ out) {
    const int nb = blockIdx.x;                 // molecules 2nb, 2nb+1
    const int tid = threadIdx.x;
    const int lane = tid & 63;
    const int wave = tid >> 6;
    const int arow = lane & 15;
    const int quad = lane >> 4;
    const int kgrp = quad * 8;

    __shared__ __attribute__((aligned(16))) unsigned char lds[36864];
    __shared__ float r_lds[2][MA][4];          // xyz + mask per molecule

    const int N = gridDim.x * 2;
    const int n0 = nb * 2;
    const float* hg0 = h + (size_t)n0 * MA * F;

    // ---- z / r passthrough + r/mask staging (both molecules) ----
    if (tid < 2 * MA) {
        int zi = z[n0 * MA + tid];
        out[(size_t)n0 * MA + tid] = (float)zi;
        int mol = tid >> 6, a = tid & 63;
        r_lds[mol][a][0] = rr[(n0 * MA + tid) * 3 + 0];
        r_lds[mol][a][1] = rr[(n0 * MA + tid) * 3 + 1];
        r_lds[mol][a][2] = rr[(n0 * MA + tid) * 3 + 2];
        r_lds[mol][a][3] = (zi > -1) ? 1.0f : 0.0f;
    }
    if (tid < 2 * MA * 3)
        out[(size_t)N * MA + (size_t)n0 * MA * 3 + tid] = rr[(size_t)n0 * MA * 3 + tid];

    // ---- stage h -> ub (row-major fp8, both molecules) ----
    for (int i = tid; i < 2 * MA * F / 4; i += 512) {
        float4 v = ((const float4*)hg0)[i];
        int mol = i >> 11;                     // 2048 float4 per molecule
        int j = i & 2047;
        int a = j >> 5, c4 = (j & 31) * 4;
        *(unsigned int*)&lds[mol * UBSZ + a * LDUB + c4] = pk4fp8(v.x, v.y, v.z, v.w);
    }
    // ---- hT A-fragments held in registers (bf16): lane holds h[b][c], c = wave*16+arow ----
    short8 ah[2][2];
    {
        int c = wave * 16 + arow;
        #pragma unroll
        for (int mol = 0; mol < 2; mol++) {
            const float* hm = hg0 + mol * MA * F;
            #pragma unroll
            for (int ks2 = 0; ks2 < 2; ks2++)
                #pragma unroll
                for (int j = 0; j < 8; j++)
                    ah[mol][ks2][j] = (short)f2bf1(hm[(size_t)(ks2 * 32 + kgrp + j) * F + c]);
        }
    }
    __syncthreads();                           // r_lds + staged h visible

    // ---- per-thread pairwise distances, mask folded in (d+1e4 -> exp underflows to 0) ----
    const int wa = tid >> 3;
    const int wb0 = (tid & 7) * 8;
    float dpre[2][8];
    #pragma unroll
    for (int mol = 0; mol < 2; mol++) {
        float ax = r_lds[mol][wa][0], ay = r_lds[mol][wa][1], az = r_lds[mol][wa][2];
        float am = r_lds[mol][wa][3];
        #pragma unroll
        for (int j = 0; j < 8; j++) {
            float dx = ax - r_lds[mol][wb0 + j][0];
            float dy = ay - r_lds[mol][wb0 + j][1];
            float dz = az - r_lds[mol][wb0 + j][2];
            float d = sqrtf(dx * dx + dy * dy + dz * dz + 1e-12f);
            float mm = am * r_lds[mol][wb0 + j][3];
            dpre[mol][j] = d + (1.0f - mm) * 1e4f;
        }
    }

    // ---- prime: w filter 0 -> wL (bf16), A-frags for seg 0 ----
    {
        float mu = dist[0];
        float isg = 1.0f / wid[0];
        #pragma unroll
        for (int mol = 0; mol < 2; mol++) {
            float e[8];
            #pragma unroll
            for (int j = 0; j < 8; j++) {
                float t = dpre[mol][j] - mu;
                e[j] = 5.0f * __expf(-t * t * isg);
            }
            uint4 wp = { pack2bf(e[0], e[1]), pack2bf(e[2], e[3]),
                         pack2bf(e[4], e[5]), pack2bf(e[6], e[7]) };
            *(uint4*)&lds[WLB + mol * WLSZ + wa * LDWB + wb0 * 2] = wp;
        }
    }
    int8v afr[4];                              // MX A-frags: 32 B/lane each
    #pragma unroll
    for (int mt = 0; mt < 4; mt++)
        afr[mt] = *(const int8v*)(w1p + ((size_t)((wave * 4 + mt) * 64 + lane)) * 32);
    __syncthreads();                           // w filter 0 visible

    const float4v zf = {0.f, 0.f, 0.f, 0.f};
    float4v acc[2][4][4];                      // [mol][j-tile in wave's 64-slab][a-tile]
    #pragma unroll
    for (int m = 0; m < 2; m++)
        #pragma unroll
        for (int i = 0; i < 4; i++)
            #pragma unroll
            for (int jv = 0; jv < 4; jv++) acc[m][i][jv] = zf;

    // ---- main loop: 17 K-segments of 128.  Schedule (0-based filters):
    //  iter f A: [GEMM1 seg f (MX fp8 K=128, scales=1.0, reads ub; per-mol sections,
    //             sched-fenced to cap live B-frags)  ->  afr(f+1) prefetch  ->
    //             u-GEMM u_f = hT @ w_f (bf16, reads wL; -> udp regs)]   -> barrier 1
    //  iter f B: [udp -> ub; exp w_{f+1} -> wL]                          -> barrier 2
    for (int f = 0; f <= NF; f++) {
        // GEMM1 seg f: one K=128 scale-MFMA per (mol,mt,at); E8M0 scale 127 = 1.0.
        // Per-mol sections + sched fence: at most 4 B-frags (32 VGPRs) live at once.
        #pragma unroll
        for (int mol = 0; mol < 2; mol++) {
            #pragma unroll
            for (int at = 0; at < 4; at++) {
                int8v bfr = *(const int8v*)&lds[mol * UBSZ + (at * 16 + arow) * LDUB + quad * 32];
                #pragma unroll
                for (int mt = 0; mt < 4; mt++)
                    acc[mol][mt][at] = __builtin_amdgcn_mfma_scale_f32_16x16x128_f8f6f4(
                        afr[mt], bfr, acc[mol][mt][at], 0, 0, 0, 127, 0, 127);
            }
            __builtin_amdgcn_sched_barrier(0); // fence: no cross-section hoisting
        }

        unsigned int udp[2][4];                // packed fp8 u_f fragments (held over barrier 1)
        if (f < NF) {
            // prefetch A-frags for seg f+1 (afr regs dead here; loads ride through
            // u-GEMM + barrier 1 + interval B; barrier 2's drain completes them)
            const unsigned char* pN = w1p + ((size_t)(((f + 1) * 32 + wave * 4) * 64 + lane)) * 32;
            #pragma unroll
            for (int mt = 0; mt < 4; mt++) afr[mt] = *(const int8v*)(pN + mt * 2048);

            // u-GEMM: u_f^T = hT @ w_f (bf16, w symmetric); no LDS write here
            #pragma unroll
            for (int mol = 0; mol < 2; mol++) {
                float4v ud[4];
                #pragma unroll
                for (int at = 0; at < 4; at++) ud[at] = zf;
                #pragma unroll
                for (int ks2 = 0; ks2 < 2; ks2++)
                    #pragma unroll
                    for (int at = 0; at < 4; at++) {
                        short8 bw = *(const short8*)&lds[WLB + mol * WLSZ + (at * 16 + arow) * LDWB + (ks2 * 32 + kgrp) * 2];
                        ud[at] = __builtin_amdgcn_mfma_f32_16x16x32_bf16(ah[mol][ks2], bw, ud[at], 0, 0, 0);
                    }
                #pragma unroll
                for (int at = 0; at < 4; at++)
                    udp[mol][at] = pk4fp8(ud[at][0], ud[at][1], ud[at][2], ud[at][3]);
            }
        }
        __syncthreads();                       // barrier 1: ub + wL reads done

        if (f < NF) {
            // B: store u_f over ub (readers drained); exp w_{f+1} -> wL
            #pragma unroll
            for (int mol = 0; mol < 2; mol++)
                #pragma unroll
                for (int at = 0; at < 4; at++)
                    *(unsigned int*)&lds[mol * UBSZ + (at * 16 + arow) * LDUB + wave * 16 + quad * 4] = udp[mol][at];

            if (f <= NF - 2) {                 // exp w_{f+1} -> wL
                float mu = dist[f + 1];
                float isg = 1.0f / wid[f + 1];
                #pragma unroll
                for (int mol = 0; mol < 2; mol++) {
                    float e[8];
                    #pragma unroll
                    for (int j = 0; j < 8; j++) {
                        float t = dpre[mol][j] - mu;
                        e[j] = 5.0f * __expf(-t * t * isg);
                    }
                    uint4 wp = { pack2bf(e[0], e[1]), pack2bf(e[2], e[3]),
                                 pack2bf(e[4], e[5]), pack2bf(e[6], e[7]) };
                    *(uint4*)&lds[WLB + mol * WLSZ + wa * LDWB + wb0 * 2] = wp;
                }
            }
            __syncthreads();                   // barrier 2: u_f + w_{f+1} visible; A loads done
        }
    }

    // ---- GEMM2 (bf16): out = h + 0.1*mask*(silu(t1) @ W2 + b2); 4 half-tiles ----
    float4 b1v[4];
    #pragma unroll
    for (int mt = 0; mt < 4; mt++)
        b1v[mt] = *(const float4*)&b1[wave * 64 + mt * 16 + quad * 4];
    float* outh0 = out + (size_t)N * MA * 4 + (size_t)n0 * MA * F;

    #pragma unroll
    for (int half = 0; half < 4; half++) {
        const int mol = half >> 1, hh = half & 1;
        if (half) __syncthreads();             // prior GEMM2 reads of t1 done
        #pragma unroll
        for (int mt = 0; mt < 4; mt++) {
            #pragma unroll
            for (int ai = 0; ai < 2; ai++) {
                const int at = hh * 2 + ai;
                float xs[4];
                #pragma unroll
                for (int r = 0; r < 4; r++) {
                    float x = acc[mol][mt][at][r] + ((const float*)&b1v[mt])[r];
                    xs[r] = x / (1.0f + __expf(-x));
                }
                uint2 pv = { pack2bf(xs[0], xs[1]), pack2bf(xs[2], xs[3]) };
                *(uint2*)&lds[(ai * 16 + arow) * LDT1B + (wave * 64 + mt * 16 + quad * 4) * 2] = pv;
            }
        }
        __syncthreads();                       // t1 half visible

        float4v g2[2] = {zf, zf};
        for (int ks = 0; ks < 16; ks++) {
            short8 aw2 = *(const short8*)(w2p + ((size_t)(ks * 8 + wave) * 64 + lane) * 8);
            #pragma unroll
            for (int n2 = 0; n2 < 2; n2++) {
                short8 bt = *(const short8*)&lds[(n2 * 16 + arow) * LDT1B + (ks * 32 + kgrp) * 2];
                g2[n2] = __builtin_amdgcn_mfma_f32_16x16x32_bf16(aw2, bt, g2[n2], 0, 0, 0);
            }
        }
        // D[m=c][n=a]: a = hh*32+n2*16+arow, c = wave*16+quad*4 + r
        const float* hgm = hg0 + mol * MA * F;
        float* outh = outh0 + mol * MA * F;
        #pragma unroll
        for (int n2 = 0; n2 < 2; n2++) {
            int a = hh * 32 + n2 * 16 + arow;
            int c0 = wave * 16 + quad * 4;
            float m = r_lds[mol][a][3] * 0.1f;
            float4 hv = *(const float4*)&hgm[a * F + c0];
            float4 b2v = *(const float4*)&b2[c0];
            float4 res;
            res.x = hv.x + (g2[n2][0] + b2v.x) * m;
            res.y = hv.y + (g2[n2][1] + b2v.y) * m;
            res.z = hv.z + (g2[n2][2] + b2v.z) * m;
            res.w = hv.w + (g2[n2][3] + b2v.w) * m;
            *(float4*)&outh[(size_t)a * F + c0] = res;
        }
    }
}

extern "C" void kernel_launch(void* const* d_in, const int* in_sizes, int n_in,
                              void* d_out, int out_size, void* d_ws, size_t ws_size,
                              hipStream_t stream) {
    const int*   z    = (const int*)d_in[0];
    const float* rr   = (const float*)d_in[1];
    const float* h    = (const float*)d_in[2];
    const float* dist = (const float*)d_in[3];
    const float* wid  = (const float*)d_in[4];
    const float* W1   = (const float*)d_in[5];
    const float* b1   = (const float*)d_in[6];
    const float* W2   = (const float*)d_in[7];
    const float* b2   = (const float*)d_in[8];
    float* out = (float*)d_out;

    int Nmol = in_sizes[0] / MA;                           // 512 molecules

    unsigned char*  w1p = (unsigned char*)d_ws;            // 544*64*32 = 1,114,112 B
    unsigned short* w2p = (unsigned short*)(w1p + (size_t)544 * 64 * 32);  // 128 KB bf16

    pack_frags<<<168, 256, 0, stream>>>(W1, W2, w1p, w2p);
    node_conv_mfma<<<Nmol / 2, 512, 0, stream>>>(z, rr, h, dist, wid, b1, b2, w1p, w2p, out);
}

// Round 11
// 154.502 us; speedup vs baseline: 1.5305x; 1.5305x over previous
//
#include <hip/hip_runtime.h>

#define MA 64
#define F 128
#define NF 16
#define HID 512
#define LDUB 144    // ub row stride BYTES (128 fp8 + 16 pad; 16B-aligned, 2-way banks)
#define WLB  9216   // wL base byte offset (ub is 64 x 144 = 9216 B)
#define LDWB 144    // wL row stride bytes (64 bf16 + 8 pad elems)
#define LDT1B 1040  // t1 row stride bytes (512 bf16 + 8 pad elems)

typedef float  float4v __attribute__((ext_vector_type(4)));
typedef short  short8  __attribute__((ext_vector_type(8)));
typedef int    int8v   __attribute__((ext_vector_type(8)));

// pack two fp32 -> (bf16(y)<<16)|bf16(x), round-half-up via +0x8000 then v_perm
static __device__ __forceinline__ unsigned int pack2bf(float x, float y) {
    unsigned int a = __float_as_uint(x) + 0x8000u;
    unsigned int b = __float_as_uint(y) + 0x8000u;
    return __builtin_amdgcn_perm(b, a, 0x07060302u);
}
static __device__ __forceinline__ unsigned short f2bf1(float x) {
    return (unsigned short)((__float_as_uint(x) + 0x8000u) >> 16);
}
// pack 4 fp32 -> 4 fp8 e4m3 (RNE, saturating) in one dword
static __device__ __forceinline__ unsigned int pk4fp8(float a, float b, float c, float d) {
    int p = __builtin_amdgcn_cvt_pk_fp8_f32(a, b, 0, false);
    p = __builtin_amdgcn_cvt_pk_fp8_f32(c, d, p, true);
    return (unsigned int)p;
}

// ---- Pack W1 as fp8 MX A-frags (16x16x128: lane l holds A[m0+(l&15)][k0+(l>>4)*32+j],
// j=0..31 = 32 bytes) of W1^T; W2 as bf16 A-frags (16x16x32) of W2^T. Direct gather.
__global__ void pack_frags(const float* __restrict__ W1, const float* __restrict__ W2,
                           unsigned char* __restrict__ w1p, unsigned short* __restrict__ w2p) {
    int gid  = blockIdx.x * 4 + (threadIdx.x >> 6);
    int lane = threadIdx.x & 63;
    int arow = lane & 15;
    int kq   = lane >> 4;
    if (gid < 544) {                           // W1: kt (17 over K=2176, 128 each) x jt (32)
        int kt = gid >> 5, jt = gid & 31;
        const float* base = W1 + (size_t)(kt * 128 + kq * 32) * HID + jt * 16 + arow;
        unsigned int o[8];
        #pragma unroll
        for (int p = 0; p < 8; p++)
            o[p] = pk4fp8(base[(p * 4 + 0) * HID], base[(p * 4 + 1) * HID],
                          base[(p * 4 + 2) * HID], base[(p * 4 + 3) * HID]);
        unsigned char* dst = w1p + ((size_t)gid * 64 + lane) * 32;
        *(uint4*)dst        = (uint4){o[0], o[1], o[2], o[3]};
        *(uint4*)(dst + 16) = (uint4){o[4], o[5], o[6], o[7]};
    } else if (gid < 544 + 128) {              // W2: kt (16 over J=512) x mt (8 over 128)
        int g2 = gid - 544;
        int kt = g2 >> 3, mt = g2 & 7;
        const float* base = W2 + (size_t)(kt * 32 + kq * 8) * F + mt * 16 + arow;
        short8 o;
        #pragma unroll
        for (int j = 0; j < 8; j++) o[j] = (short)f2bf1(base[j * F]);
        *(short8*)(w2p + ((size_t)g2 * 64 + lane) * 8) = o;
    }
}

// ---- Main fused kernel: ONE molecule per block, 512 threads = 8 waves ----
// LDS bytes: ub @0 (9216) | wL @9216 (9216) = 18432 B live in main loop.
// t1 bf16 (32 x 1040 = 33280 B) overlays from 0 during GEMM2. lds[] sized for t1.
// acc = 64 AGPRs (1 mol) -> ~190 VGPR headroom for MX operands; no spills.
__launch_bounds__(512, 2)
__global__ void node_conv_mfma(const int* __restrict__ z, const float* __restrict__ rr,
        const float* __restrict__ h, const float* __restrict__ dist,
        const float* __restrict__ wid, const float* __restrict__ b1,
        const float* __restrict__ b2,
        const unsigned char* __restrict__ w1p, const unsigned short* __restrict__ w2p,
        float* __restrict__ out) {
    const int n = blockIdx.x;                  // molecule index
    const int tid = threadIdx.x;
    const int lane = tid & 63;
    const int wave = tid >> 6;
    const int arow = lane & 15;
    const int quad = lane >> 4;
    const int kgrp = quad * 8;

    __shared__ __attribute__((aligned(16))) unsigned char lds[33280];
    __shared__ float r_lds[MA][4];             // xyz + mask

    const int N = gridDim.x;
    const float* hg = h + (size_t)n * MA * F;

    // ---- z / r passthrough + r/mask staging ----
    if (tid < MA) {
        int zi = z[n * MA + tid];
        out[(size_t)n * MA + tid] = (float)zi;
        r_lds[tid][0] = rr[(n * MA + tid) * 3 + 0];
        r_lds[tid][1] = rr[(n * MA + tid) * 3 + 1];
        r_lds[tid][2] = rr[(n * MA + tid) * 3 + 2];
        r_lds[tid][3] = (zi > -1) ? 1.0f : 0.0f;
    }
    if (tid < MA * 3)
        out[(size_t)N * MA + (size_t)n * MA * 3 + tid] = rr[(size_t)n * MA * 3 + tid];

    // ---- stage h -> ub (row-major fp8) ----
    for (int i = tid; i < MA * F / 4; i += 512) {
        float4 v = ((const float4*)hg)[i];
        int a = i >> 5, c4 = (i & 31) * 4;
        *(unsigned int*)&lds[a * LDUB + c4] = pk4fp8(v.x, v.y, v.z, v.w);
    }
    // ---- hT A-fragments held in registers (bf16): lane holds h[b][c], c = wave*16+arow ----
    short8 ah[2];
    {
        int c = wave * 16 + arow;
        #pragma unroll
        for (int ks2 = 0; ks2 < 2; ks2++)
            #pragma unroll
            for (int j = 0; j < 8; j++)
                ah[ks2][j] = (short)f2bf1(hg[(size_t)(ks2 * 32 + kgrp + j) * F + c]);
    }
    __syncthreads();                           // r_lds + staged h visible

    // ---- per-thread pairwise distances, mask folded in (d+1e4 -> exp underflows to 0) ----
    const int wa = tid >> 3;
    const int wb0 = (tid & 7) * 8;
    float dpre[8];
    {
        float ax = r_lds[wa][0], ay = r_lds[wa][1], az = r_lds[wa][2];
        float am = r_lds[wa][3];
        #pragma unroll
        for (int j = 0; j < 8; j++) {
            float dx = ax - r_lds[wb0 + j][0];
            float dy = ay - r_lds[wb0 + j][1];
            float dz = az - r_lds[wb0 + j][2];
            float d = sqrtf(dx * dx + dy * dy + dz * dz + 1e-12f);
            float mm = am * r_lds[wb0 + j][3];
            dpre[j] = d + (1.0f - mm) * 1e4f;
        }
    }

    // ---- prime: w filter 0 -> wL (bf16), A-frags for seg 0 ----
    {
        float mu = dist[0];
        float isg = 1.0f / wid[0];
        float e[8];
        #pragma unroll
        for (int j = 0; j < 8; j++) {
            float t = dpre[j] - mu;
            e[j] = 5.0f * __expf(-t * t * isg);
        }
        uint4 wp = { pack2bf(e[0], e[1]), pack2bf(e[2], e[3]),
                     pack2bf(e[4], e[5]), pack2bf(e[6], e[7]) };
        *(uint4*)&lds[WLB + wa * LDWB + wb0 * 2] = wp;
    }
    int8v afr[4];                              // MX A-frags: 32 B/lane each
    #pragma unroll
    for (int mt = 0; mt < 4; mt++)
        afr[mt] = *(const int8v*)(w1p + ((size_t)((wave * 4 + mt) * 64 + lane)) * 32);
    __syncthreads();                           // w filter 0 visible

    const float4v zf = {0.f, 0.f, 0.f, 0.f};
    float4v acc[4][4];                         // [j-tile in wave's 64-slab][a-tile] = 64 AGPRs
    #pragma unroll
    for (int i = 0; i < 4; i++)
        #pragma unroll
        for (int jv = 0; jv < 4; jv++) acc[i][jv] = zf;

    // ---- main loop: 17 K-segments of 128.  Schedule (0-based filters):
    //  iter f A: [GEMM1 seg f (MX fp8 K=128, scales=1.0, reads ub)  ->
    //             afr(f+1) prefetch (afr dead)  ->
    //             u-GEMM u_f = hT @ w_f (bf16, reads wL; -> udp regs)]   -> barrier 1
    //  iter f B: [udp -> ub; exp w_{f+1} -> wL]                          -> barrier 2
    for (int f = 0; f <= NF; f++) {
        // GEMM1 seg f: one K=128 scale-MFMA per (mt,at); E8M0 scale 127 = 1.0
        #pragma unroll
        for (int at = 0; at < 4; at++) {
            int8v bfr = *(const int8v*)&lds[(at * 16 + arow) * LDUB + quad * 32];
            #pragma unroll
            for (int mt = 0; mt < 4; mt++)
                acc[mt][at] = __builtin_amdgcn_mfma_scale_f32_16x16x128_f8f6f4(
                    afr[mt], bfr, acc[mt][at], 0, 0, 0, 127, 0, 127);
        }

        unsigned int udp[4];                   // packed fp8 u_f fragments (held over barrier 1)
        if (f < NF) {
            // prefetch A-frags for seg f+1 (afr regs dead here; loads ride through
            // u-GEMM + barrier 1 + interval B; barrier 2's drain completes them)
            const unsigned char* pN = w1p + ((size_t)(((f + 1) * 32 + wave * 4) * 64 + lane)) * 32;
            #pragma unroll
            for (int mt = 0; mt < 4; mt++) afr[mt] = *(const int8v*)(pN + mt * 2048);

            // u-GEMM: u_f^T = hT @ w_f (bf16, w symmetric); no LDS write here
            float4v ud[4];
            #pragma unroll
            for (int at = 0; at < 4; at++) ud[at] = zf;
            #pragma unroll
            for (int ks2 = 0; ks2 < 2; ks2++)
                #pragma unroll
                for (int at = 0; at < 4; at++) {
                    short8 bw = *(const short8*)&lds[WLB + (at * 16 + arow) * LDWB + (ks2 * 32 + kgrp) * 2];
                    ud[at] = __builtin_amdgcn_mfma_f32_16x16x32_bf16(ah[ks2], bw, ud[at], 0, 0, 0);
                }
            #pragma unroll
            for (int at = 0; at < 4; at++)
                udp[at] = pk4fp8(ud[at][0], ud[at][1], ud[at][2], ud[at][3]);
        }
        __syncthreads();                       // barrier 1: ub + wL reads done

        if (f < NF) {
            // B: store u_f over ub (readers drained); exp w_{f+1} -> wL
            #pragma unroll
            for (int at = 0; at < 4; at++)
                *(unsigned int*)&lds[(at * 16 + arow) * LDUB + wave * 16 + quad * 4] = udp[at];

            if (f <= NF - 2) {                 // exp w_{f+1} -> wL
                float mu = dist[f + 1];
                float isg = 1.0f / wid[f + 1];
                float e[8];
                #pragma unroll
                for (int j = 0; j < 8; j++) {
                    float t = dpre[j] - mu;
                    e[j] = 5.0f * __expf(-t * t * isg);
                }
                uint4 wp = { pack2bf(e[0], e[1]), pack2bf(e[2], e[3]),
                             pack2bf(e[4], e[5]), pack2bf(e[6], e[7]) };
                *(uint4*)&lds[WLB + wa * LDWB + wb0 * 2] = wp;
            }
            __syncthreads();                   // barrier 2: u_f + w_{f+1} visible; A loads done
        }
    }

    // ---- GEMM2 (bf16): out = h + 0.1*mask*(silu(t1) @ W2 + b2); 2 half-tiles ----
    float4 b1v[4];
    #pragma unroll
    for (int mt = 0; mt < 4; mt++)
        b1v[mt] = *(const float4*)&b1[wave * 64 + mt * 16 + quad * 4];
    float* outh = out + (size_t)N * MA * 4 + (size_t)n * MA * F;

    #pragma unroll
    for (int hh = 0; hh < 2; hh++) {
        if (hh) __syncthreads();               // prior GEMM2 reads of t1 done
        #pragma unroll
        for (int mt = 0; mt < 4; mt++) {
            #pragma unroll
            for (int ai = 0; ai < 2; ai++) {
                const int at = hh * 2 + ai;
                float xs[4];
                #pragma unroll
                for (int r = 0; r < 4; r++) {
                    float x = acc[mt][at][r] + ((const float*)&b1v[mt])[r];
                    xs[r] = x / (1.0f + __expf(-x));
                }
                uint2 pv = { pack2bf(xs[0], xs[1]), pack2bf(xs[2], xs[3]) };
                *(uint2*)&lds[(ai * 16 + arow) * LDT1B + (wave * 64 + mt * 16 + quad * 4) * 2] = pv;
            }
        }
        __syncthreads();                       // t1 half visible

        float4v g2[2] = {zf, zf};
        for (int ks = 0; ks < 16; ks++) {
            short8 aw2 = *(const short8*)(w2p + ((size_t)(ks * 8 + wave) * 64 + lane) * 8);
            #pragma unroll
            for (int n2 = 0; n2 < 2; n2++) {
                short8 bt = *(const short8*)&lds[(n2 * 16 + arow) * LDT1B + (ks * 32 + kgrp) * 2];
                g2[n2] = __builtin_amdgcn_mfma_f32_16x16x32_bf16(aw2, bt, g2[n2], 0, 0, 0);
            }
        }
        // D[m=c][n=a]: a = hh*32+n2*16+arow, c = wave*16+quad*4 + r
        #pragma unroll
        for (int n2 = 0; n2 < 2; n2++) {
            int a = hh * 32 + n2 * 16 + arow;
            int c0 = wave * 16 + quad * 4;
            float m = r_lds[a][3] * 0.1f;
            float4 hv = *(const float4*)&hg[a * F + c0];
            float4 b2v = *(const float4*)&b2[c0];
            float4 res;
            res.x = hv.x + (g2[n2][0] + b2v.x) * m;
            res.y = hv.y + (g2[n2][1] + b2v.y) * m;
            res.z = hv.z + (g2[n2][2] + b2v.z) * m;
            res.w = hv.w + (g2[n2][3] + b2v.w) * m;
            *(float4*)&outh[(size_t)a * F + c0] = res;
        }
    }
}

extern "C" void kernel_launch(void* const* d_in, const int* in_sizes, int n_in,
                              void* d_out, int out_size, void* d_ws, size_t ws_size,
                              hipStream_t stream) {
    const int*   z    = (const int*)d_in[0];
    const float* rr   = (const float*)d_in[1];
    const float* h    = (const float*)d_in[2];
    const float* dist = (const float*)d_in[3];
    const float* wid  = (const float*)d_in[4];
    const float* W1   = (const float*)d_in[5];
    const float* b1   = (const float*)d_in[6];
    const float* W2   = (const float*)d_in[7];
    const float* b2   = (const float*)d_in[8];
    float* out = (float*)d_out;

    int Nmol = in_sizes[0] / MA;                           // 512 molecules

    unsigned char*  w1p = (unsigned char*)d_ws;            // 544*64*32 = 1,114,112 B
    unsigned short* w2p = (unsigned short*)(w1p + (size_t)544 * 64 * 32);  // 128 KB bf16

    pack_frags<<<168, 256, 0, stream>>>(W1, W2, w1p, w2p);
    node_conv_mfma<<<Nmol, 512, 0, stream>>>(z, rr, h, dist, wid, b1, b2, w1p, w2p, out);
}